// Round 1
// baseline (6642.743 us; speedup 1.0000x reference)
//
#include <hip/hip_runtime.h>

#define QLEN 2048
#define KVTOT 4096
#define DMODEL 1024
#define NHEAD 16
#define HDIM 64

typedef __attribute__((ext_vector_type(8))) short bf16x8;
typedef __attribute__((ext_vector_type(4))) float f32x4;

__device__ __forceinline__ unsigned short f2b(float f) {
  union { float f; unsigned u; } v; v.f = f;
  unsigned r = v.u + 0x7FFFu + ((v.u >> 16) & 1u);
  return (unsigned short)(r >> 16);
}

// ---------------------------------------------------------------------------
// Copy past_k/past_v (B,2048,1024) into k_cat/v_cat (B,4096,1024) rows 0..2047
// ---------------------------------------------------------------------------
__global__ __launch_bounds__(256) void copy_past(
    const float* __restrict__ pk, const float* __restrict__ pv,
    float* __restrict__ kcat, float* __restrict__ vcat) {
  int i = blockIdx.x * 256 + threadIdx.x;       // 0 .. 1048575 (float4 units)
  int b = i >> 19;                               // / (2048*1024/4)
  int r = i & 524287;
  size_t src = (size_t)i * 4;
  size_t dst = ((size_t)b * 1048576 + r) * 4;    // b*4096*1024 + r*4
  *(float4*)&kcat[dst] = *(const float4*)&pk[src];
  *(float4*)&vcat[dst] = *(const float4*)&pv[src];
}

// ---------------------------------------------------------------------------
// C = A(M,K) * W(N,K)^T + bias, bf16 MFMA 16x16x32, 128x128 tile, BK=32.
// mode 0: C row = row (contiguous). mode 1: row -> b*4096 + 2048 + s (cat).
// ---------------------------------------------------------------------------
__global__ __launch_bounds__(256) void gemm_bt(
    const float* __restrict__ A, const float* __restrict__ W,
    const float* __restrict__ bias, float* __restrict__ C,
    int M, int N, int K, int mode) {
  __shared__ unsigned short As[128][40];   // +8 pad: 80B row stride, 16B aligned
  __shared__ unsigned short Bs[128][40];
  const int t = threadIdx.x;
  const int m0 = blockIdx.y * 128;
  const int n0 = blockIdx.x * 128;
  const int lane = t & 63;
  const int wid = t >> 6;
  const int wr = (wid >> 1) * 64;
  const int wc = (wid & 1) * 64;
  const int lr = lane & 15;
  const int ko = (lane >> 4) * 8;

  f32x4 acc[4][4];
  #pragma unroll
  for (int m = 0; m < 4; ++m)
    #pragma unroll
    for (int n = 0; n < 4; ++n)
      acc[m][n] = (f32x4){0.f, 0.f, 0.f, 0.f};

  for (int k0 = 0; k0 < K; k0 += 32) {
    __syncthreads();
    #pragma unroll
    for (int j = 0; j < 4; ++j) {
      int idx = t + j * 256;               // 0..1023
      int r = idx >> 3;                    // row 0..127
      int c4 = (idx & 7) * 4;              // col 0..28
      float4 va = *(const float4*)&A[(size_t)(m0 + r) * K + k0 + c4];
      As[r][c4 + 0] = f2b(va.x); As[r][c4 + 1] = f2b(va.y);
      As[r][c4 + 2] = f2b(va.z); As[r][c4 + 3] = f2b(va.w);
      float4 vb = *(const float4*)&W[(size_t)(n0 + r) * K + k0 + c4];
      Bs[r][c4 + 0] = f2b(vb.x); Bs[r][c4 + 1] = f2b(vb.y);
      Bs[r][c4 + 2] = f2b(vb.z); Bs[r][c4 + 3] = f2b(vb.w);
    }
    __syncthreads();
    bf16x8 av[4], bv[4];
    #pragma unroll
    for (int m = 0; m < 4; ++m)
      av[m] = *(const bf16x8*)&As[wr + m * 16 + lr][ko];
    #pragma unroll
    for (int n = 0; n < 4; ++n)
      bv[n] = *(const bf16x8*)&Bs[wc + n * 16 + lr][ko];
    #pragma unroll
    for (int m = 0; m < 4; ++m)
      #pragma unroll
      for (int n = 0; n < 4; ++n)
        acc[m][n] = __builtin_amdgcn_mfma_f32_16x16x32_bf16(av[m], bv[n], acc[m][n], 0, 0, 0);
  }

  const int rq = (lane >> 4) * 4;   // C/D: row = (lane>>4)*4 + reg, col = lane&15
  const int cl = lane & 15;
  #pragma unroll
  for (int m = 0; m < 4; ++m) {
    #pragma unroll
    for (int r = 0; r < 4; ++r) {
      int row = m0 + wr + m * 16 + rq + r;
      size_t orow;
      if (mode == 0) {
        orow = (size_t)row;
      } else {
        int b = row >> 11, s = row & 2047;
        orow = (size_t)(b * 4096 + 2048 + s);
      }
      float* cp = C + orow * (size_t)N;
      #pragma unroll
      for (int n = 0; n < 4; ++n) {
        int col = n0 + wc + n * 16 + cl;
        cp[col] = acc[m][n][r] + bias[col];
      }
    }
  }
}

// ---------------------------------------------------------------------------
// Vector fp32 flash attention. Block = 4 waves = 4 q rows of one (b,h).
// Online softmax; lane owns kv index in QK phase, owns dim d in PV phase.
// ---------------------------------------------------------------------------
__global__ __launch_bounds__(256) void attn_kernel(
    const float* __restrict__ qp, const float* __restrict__ kcat,
    const float* __restrict__ vcat, const int* __restrict__ mask,
    float* __restrict__ out) {
  __shared__ float klds[64][65];
  __shared__ float vlds[64][65];
  __shared__ float qlds[4][64];
  const int t = threadIdx.x;
  const int wid = t >> 6;
  const int lane = t & 63;
  const int bh = blockIdx.y;
  const int b = bh >> 4;
  const int h = bh & 15;
  const int q0 = blockIdx.x * 4;
  const int qi = q0 + wid;

  // load 4 q rows (thread t loads one element)
  {
    int qr = t >> 6, qd = t & 63;
    qlds[qr][qd] = qp[((size_t)b * QLEN + q0 + qr) * DMODEL + h * HDIM + qd];
  }

  float m = -INFINITY, lsum = 0.f, oacc = 0.f;
  const int* mrow = mask + ((size_t)b * QLEN + qi) * KVTOT;

  for (int t0 = 0; t0 < KVTOT; t0 += 64) {
    __syncthreads();
    // stage 64x64 K and V slices for this (b,h)
    #pragma unroll
    for (int j = 0; j < 4; ++j) {
      int idx = t + j * 256;               // 0..1023
      int r = idx >> 4;                    // row 0..63
      int c = (idx & 15) * 4;              // col 0..60
      size_t gi = ((size_t)b * KVTOT + t0 + r) * DMODEL + h * HDIM + c;
      float4 kk = *(const float4*)&kcat[gi];
      klds[r][c] = kk.x; klds[r][c + 1] = kk.y; klds[r][c + 2] = kk.z; klds[r][c + 3] = kk.w;
      float4 vv = *(const float4*)&vcat[gi];
      vlds[r][c] = vv.x; vlds[r][c + 1] = vv.y; vlds[r][c + 2] = vv.z; vlds[r][c + 3] = vv.w;
    }
    __syncthreads();

    // QK: lane computes score for kv = t0 + lane
    float s = 0.f;
    #pragma unroll
    for (int d = 0; d < 64; ++d) s += qlds[wid][d] * klds[lane][d];
    s *= 0.125f;
    if (mrow[t0 + lane]) s -= 10000.f;

    // online softmax update
    float tmax = s;
    #pragma unroll
    for (int off = 32; off; off >>= 1) tmax = fmaxf(tmax, __shfl_xor(tmax, off));
    float mnew = fmaxf(m, tmax);
    float corr = expf(m - mnew);           // m=-inf first tile -> 0
    float p = expf(s - mnew);
    float tsum = p;
    #pragma unroll
    for (int off = 32; off; off >>= 1) tsum += __shfl_xor(tsum, off);
    lsum = lsum * corr + tsum;
    oacc *= corr;
    // PV: lane owns output dim d = lane
    #pragma unroll
    for (int kv = 0; kv < 64; ++kv)
      oacc += __shfl(p, kv) * vlds[kv][lane];
    m = mnew;
  }

  out[((size_t)b * QLEN + qi) * DMODEL + h * HDIM + lane] = oacc / lsum;
}

// ---------------------------------------------------------------------------
extern "C" void kernel_launch(void* const* d_in, const int* in_sizes, int n_in,
                              void* d_out, int out_size, void* d_ws, size_t ws_size,
                              hipStream_t stream) {
  const float* q      = (const float*)d_in[0];
  const float* k      = (const float*)d_in[1];
  const float* v      = (const float*)d_in[2];
  const float* past_k = (const float*)d_in[3];
  const float* past_v = (const float*)d_in[4];
  const int*   mask   = (const int*)d_in[5];
  const float* Wq     = (const float*)d_in[6];
  const float* bq     = (const float*)d_in[7];
  const float* Wk     = (const float*)d_in[8];
  const float* bk     = (const float*)d_in[9];
  const float* Wv     = (const float*)d_in[10];
  const float* bv     = (const float*)d_in[11];
  const float* Wl     = (const float*)d_in[12];
  const float* bl     = (const float*)d_in[13];

  float* xout = (float*)d_out;                    // (B, Q, D)     4,194,304
  float* kcat = xout + 4194304;                   // (B, 4096, D)  8,388,608
  float* vcat = xout + 12582912;                  // (B, 4096, D)  8,388,608

  float* qp    = (float*)d_ws;                    // (4096, 1024) fp32
  float* attno = qp + 4194304;                    // (4096, 1024) fp32

  copy_past<<<4096, 256, 0, stream>>>(past_k, past_v, kcat, vcat);

  dim3 gg(8, 32);   // N/128 x M/128
  gemm_bt<<<gg, 256, 0, stream>>>(q, Wq, bq, qp,   4096, 1024, 1024, 0);
  gemm_bt<<<gg, 256, 0, stream>>>(k, Wk, bk, kcat, 4096, 1024, 1024, 1);
  gemm_bt<<<gg, 256, 0, stream>>>(v, Wv, bv, vcat, 4096, 1024, 1024, 1);

  dim3 ga(512, 32); // q-groups x (B*H)
  attn_kernel<<<ga, 256, 0, stream>>>(qp, kcat, vcat, mask, attno);

  gemm_bt<<<gg, 256, 0, stream>>>(attno, Wl, bl, xout, 4096, 1024, 1024, 0);
}

// Round 2
// 504.003 us; speedup vs baseline: 13.1800x; 13.1800x over previous
//
#include <hip/hip_runtime.h>

#define QLEN 2048
#define KVTOT 4096
#define DMODEL 1024
#define NHEAD 16
#define HDIM 64

typedef __attribute__((ext_vector_type(8))) short bf16x8;
typedef __attribute__((ext_vector_type(4))) float f32x4;
typedef unsigned short u16;

__device__ __forceinline__ u16 f2b(float f) {
  union { float f; unsigned u; } v; v.f = f;
  unsigned r = v.u + 0x7FFFu + ((v.u >> 16) & 1u);
  return (u16)(r >> 16);
}

// ---------------------------------------------------------------------------
// Copy past_k/past_v (B,2048,1024) into k_cat/v_cat (B,4096,1024) rows 0..2047
// ---------------------------------------------------------------------------
__global__ __launch_bounds__(256) void copy_past(
    const float* __restrict__ pk, const float* __restrict__ pv,
    float* __restrict__ kcat, float* __restrict__ vcat) {
  int i = blockIdx.x * 256 + threadIdx.x;       // float4 units
  int b = i >> 19;
  int r = i & 524287;
  size_t src = (size_t)i * 4;
  size_t dst = ((size_t)b * 1048576 + r) * 4;
  *(float4*)&kcat[dst] = *(const float4*)&pk[src];
  *(float4*)&vcat[dst] = *(const float4*)&pv[src];
}

// ---------------------------------------------------------------------------
// C = A(M,K) * W(N,K)^T + bias, bf16 MFMA 16x16x32, 128x128 tile, BK=32.
// mode 0: C row = row. mode 1: row -> b*4096 + 2048 + s (cat layout).
// ---------------------------------------------------------------------------
__global__ __launch_bounds__(256) void gemm_bt(
    const float* __restrict__ A, const float* __restrict__ W,
    const float* __restrict__ bias, float* __restrict__ C,
    int M, int N, int K, int mode) {
  __shared__ u16 As[128][40];
  __shared__ u16 Bs[128][40];
  const int t = threadIdx.x;
  const int m0 = blockIdx.y * 128;
  const int n0 = blockIdx.x * 128;
  const int lane = t & 63;
  const int wid = t >> 6;
  const int wr = (wid >> 1) * 64;
  const int wc = (wid & 1) * 64;
  const int lr = lane & 15;
  const int ko = (lane >> 4) * 8;

  f32x4 acc[4][4];
  #pragma unroll
  for (int m = 0; m < 4; ++m)
    #pragma unroll
    for (int n = 0; n < 4; ++n)
      acc[m][n] = (f32x4){0.f, 0.f, 0.f, 0.f};

  for (int k0 = 0; k0 < K; k0 += 32) {
    __syncthreads();
    #pragma unroll
    for (int j = 0; j < 4; ++j) {
      int idx = t + j * 256;
      int r = idx >> 3;
      int c4 = (idx & 7) * 4;
      float4 va = *(const float4*)&A[(size_t)(m0 + r) * K + k0 + c4];
      As[r][c4 + 0] = f2b(va.x); As[r][c4 + 1] = f2b(va.y);
      As[r][c4 + 2] = f2b(va.z); As[r][c4 + 3] = f2b(va.w);
      float4 vb = *(const float4*)&W[(size_t)(n0 + r) * K + k0 + c4];
      Bs[r][c4 + 0] = f2b(vb.x); Bs[r][c4 + 1] = f2b(vb.y);
      Bs[r][c4 + 2] = f2b(vb.z); Bs[r][c4 + 3] = f2b(vb.w);
    }
    __syncthreads();
    bf16x8 av[4], bv[4];
    #pragma unroll
    for (int m = 0; m < 4; ++m)
      av[m] = *(const bf16x8*)&As[wr + m * 16 + lr][ko];
    #pragma unroll
    for (int n = 0; n < 4; ++n)
      bv[n] = *(const bf16x8*)&Bs[wc + n * 16 + lr][ko];
    #pragma unroll
    for (int m = 0; m < 4; ++m)
      #pragma unroll
      for (int n = 0; n < 4; ++n)
        acc[m][n] = __builtin_amdgcn_mfma_f32_16x16x32_bf16(av[m], bv[n], acc[m][n], 0, 0, 0);
  }

  const int rq = (lane >> 4) * 4;
  const int cl = lane & 15;
  #pragma unroll
  for (int m = 0; m < 4; ++m) {
    #pragma unroll
    for (int r = 0; r < 4; ++r) {
      int row = m0 + wr + m * 16 + rq + r;
      size_t orow;
      if (mode == 0) {
        orow = (size_t)row;
      } else {
        int b = row >> 11, s = row & 2047;
        orow = (size_t)(b * 4096 + 2048 + s);
      }
      float* cp = C + orow * (size_t)N;
      #pragma unroll
      for (int n = 0; n < 4; ++n) {
        int col = n0 + wc + n * 16 + cl;
        cp[col] = acc[m][n][r] + bias[col];
      }
    }
  }
}

// ---------------------------------------------------------------------------
// repack fp32 [B][S][1024] -> bf16 head layout [B][16][S][64]
// ---------------------------------------------------------------------------
__global__ __launch_bounds__(256) void repack_h(
    const float* __restrict__ src, u16* __restrict__ dst, int S, int sshift) {
  int idx = blockIdx.x * 256 + threadIdx.x;   // chunk of 8 elems
  int d8 = (idx & 7) * 8;
  int h = (idx >> 3) & 15;
  int bs = idx >> 7;                          // = b*S + s
  int s = bs & (S - 1);
  int b = bs >> sshift;
  const float* sp = src + (size_t)bs * 1024 + h * 64 + d8;
  float4 a = *(const float4*)sp;
  float4 c = *(const float4*)(sp + 4);
  bf16x8 o;
  o[0] = (short)f2b(a.x); o[1] = (short)f2b(a.y); o[2] = (short)f2b(a.z); o[3] = (short)f2b(a.w);
  o[4] = (short)f2b(c.x); o[5] = (short)f2b(c.y); o[6] = (short)f2b(c.z); o[7] = (short)f2b(c.w);
  *(bf16x8*)(dst + ((size_t)(b * 16 + h) * S + s) * 64 + d8) = o;
}

// ---------------------------------------------------------------------------
// repack fp32 vcat [B][4096][1024] -> bf16 transposed [B][16][64][4096]
// ---------------------------------------------------------------------------
__global__ __launch_bounds__(256) void repack_vt(
    const float* __restrict__ src, u16* __restrict__ dst) {
  __shared__ u16 T[64][72];
  const int t = threadIdx.x;
  const int kv0 = blockIdx.x * 64;
  const int bh = blockIdx.y;
  const int b = bh >> 4, h = bh & 15;
  #pragma unroll
  for (int it = 0; it < 4; ++it) {
    int idx = t + it * 256;            // 0..1023
    int r = idx >> 4;                  // kv row 0..63
    int c4 = (idx & 15) * 4;           // d col
    float4 v = *(const float4*)(src + (size_t)(b * KVTOT + kv0 + r) * DMODEL + h * 64 + c4);
    T[r][c4 + 0] = f2b(v.x); T[r][c4 + 1] = f2b(v.y);
    T[r][c4 + 2] = f2b(v.z); T[r][c4 + 3] = f2b(v.w);
  }
  __syncthreads();
  #pragma unroll
  for (int it = 0; it < 2; ++it) {
    int idx = t + it * 256;            // 0..511
    int d = idx & 63;
    int kc8 = (idx >> 6) * 8;
    bf16x8 o;
    #pragma unroll
    for (int j = 0; j < 8; ++j) o[j] = (short)T[kc8 + j][d];
    *(bf16x8*)(dst + (size_t)((b * 16 + h) * 64 + d) * KVTOT + kv0 + kc8) = o;
  }
}

// ---------------------------------------------------------------------------
// MFMA flash attention. 4 waves, 64-q tile per (b,h); KV tiles of 64.
// ---------------------------------------------------------------------------
__global__ __launch_bounds__(256) void attn_mfma(
    const u16* __restrict__ qh, const u16* __restrict__ kh,
    const u16* __restrict__ vt, const int* __restrict__ mask,
    float* __restrict__ out) {
  __shared__ u16 Kl[64][72];
  __shared__ u16 Vl[64][72];
  __shared__ u16 Pl[4][16][72];
  const int t = threadIdx.x;
  const int wid = t >> 6, lane = t & 63;
  const int lr = lane & 15, lg = lane >> 4;
  const int bh = blockIdx.y, b = bh >> 4, h = bh & 15;
  const int q0 = blockIdx.x * 64;
  const int qw = q0 + wid * 16;

  bf16x8 qf[2];
  {
    const u16* qp = qh + ((size_t)bh * QLEN + qw + lr) * 64 + lg * 8;
    qf[0] = *(const bf16x8*)qp;
    qf[1] = *(const bf16x8*)(qp + 32);
  }

  const size_t khb = (size_t)bh * KVTOT * 64;
  const size_t vtb = (size_t)bh * 64 * KVTOT;
  const int* mp = mask + (size_t)b * QLEN * KVTOT;
  int moff[4];
  #pragma unroll
  for (int r = 0; r < 4; ++r) moff[r] = (qw + lg * 4 + r) * KVTOT + lr;

  float mrow[4] = {-1e30f, -1e30f, -1e30f, -1e30f};
  float lrow[4] = {0.f, 0.f, 0.f, 0.f};
  f32x4 oacc[4];
  #pragma unroll
  for (int dt = 0; dt < 4; ++dt) oacc[dt] = (f32x4){0.f, 0.f, 0.f, 0.f};

  for (int t0 = 0; t0 < KVTOT; t0 += 64) {
    __syncthreads();
    #pragma unroll
    for (int it = 0; it < 2; ++it) {
      int idx = t + it * 256;
      int r = idx >> 3, c8 = (idx & 7) * 8;
      *(bf16x8*)&Kl[r][c8] = *(const bf16x8*)(kh + khb + (size_t)(t0 + r) * 64 + c8);
      *(bf16x8*)&Vl[r][c8] = *(const bf16x8*)(vt + vtb + (size_t)r * KVTOT + t0 + c8);
    }
    __syncthreads();

    // QK^T: S[q=lg*4+r][kv=tile*16+lr]
    f32x4 sacc[4];
    #pragma unroll
    for (int tile = 0; tile < 4; ++tile) sacc[tile] = (f32x4){0.f, 0.f, 0.f, 0.f};
    #pragma unroll
    for (int tile = 0; tile < 4; ++tile) {
      bf16x8 kf0 = *(const bf16x8*)&Kl[tile * 16 + lr][lg * 8];
      bf16x8 kf1 = *(const bf16x8*)&Kl[tile * 16 + lr][32 + lg * 8];
      sacc[tile] = __builtin_amdgcn_mfma_f32_16x16x32_bf16(qf[0], kf0, sacc[tile], 0, 0, 0);
      sacc[tile] = __builtin_amdgcn_mfma_f32_16x16x32_bf16(qf[1], kf1, sacc[tile], 0, 0, 0);
    }

    // scale + mask
    float sv[4][4];
    #pragma unroll
    for (int tile = 0; tile < 4; ++tile)
      #pragma unroll
      for (int r = 0; r < 4; ++r) {
        int mv = mp[moff[r] + t0 + tile * 16];
        sv[tile][r] = sacc[tile][r] * 0.125f + (mv ? -10000.f : 0.f);
      }

    // online softmax per q row (rows live in reg index r; reduce over 16 lanes)
    float corr[4];
    #pragma unroll
    for (int r = 0; r < 4; ++r) {
      float v = fmaxf(fmaxf(sv[0][r], sv[1][r]), fmaxf(sv[2][r], sv[3][r]));
      #pragma unroll
      for (int off = 8; off; off >>= 1) v = fmaxf(v, __shfl_xor(v, off));
      float mnew = fmaxf(mrow[r], v);
      corr[r] = __expf(mrow[r] - mnew);
      mrow[r] = mnew;
    }

    float rsum[4] = {0.f, 0.f, 0.f, 0.f};
    #pragma unroll
    for (int tile = 0; tile < 4; ++tile)
      #pragma unroll
      for (int r = 0; r < 4; ++r) {
        float p = __expf(sv[tile][r] - mrow[r]);
        rsum[r] += p;
        Pl[wid][lg * 4 + r][tile * 16 + lr] = f2b(p);
      }
    #pragma unroll
    for (int r = 0; r < 4; ++r) {
      float v = rsum[r];
      #pragma unroll
      for (int off = 8; off; off >>= 1) v += __shfl_xor(v, off);
      lrow[r] = lrow[r] * corr[r] + v;
    }
    #pragma unroll
    for (int dt = 0; dt < 4; ++dt)
      #pragma unroll
      for (int r = 0; r < 4; ++r) oacc[dt][r] *= corr[r];

    // PV: O[q][d] += P[q][kv] * V[kv][d] ; P wave-private in LDS (no barrier)
    bf16x8 pa0 = *(const bf16x8*)&Pl[wid][lr][lg * 8];
    bf16x8 pa1 = *(const bf16x8*)&Pl[wid][lr][32 + lg * 8];
    #pragma unroll
    for (int dt = 0; dt < 4; ++dt) {
      bf16x8 vb0 = *(const bf16x8*)&Vl[dt * 16 + lr][lg * 8];
      bf16x8 vb1 = *(const bf16x8*)&Vl[dt * 16 + lr][32 + lg * 8];
      oacc[dt] = __builtin_amdgcn_mfma_f32_16x16x32_bf16(pa0, vb0, oacc[dt], 0, 0, 0);
      oacc[dt] = __builtin_amdgcn_mfma_f32_16x16x32_bf16(pa1, vb1, oacc[dt], 0, 0, 0);
    }
  }

  float inv[4];
  #pragma unroll
  for (int r = 0; r < 4; ++r) inv[r] = 1.f / lrow[r];
  #pragma unroll
  for (int dt = 0; dt < 4; ++dt)
    #pragma unroll
    for (int r = 0; r < 4; ++r)
      out[((size_t)b * QLEN + qw + lg * 4 + r) * DMODEL + h * 64 + dt * 16 + lr] =
          oacc[dt][r] * inv[r];
}

// ---------------------------------------------------------------------------
extern "C" void kernel_launch(void* const* d_in, const int* in_sizes, int n_in,
                              void* d_out, int out_size, void* d_ws, size_t ws_size,
                              hipStream_t stream) {
  const float* q      = (const float*)d_in[0];
  const float* k      = (const float*)d_in[1];
  const float* v      = (const float*)d_in[2];
  const float* past_k = (const float*)d_in[3];
  const float* past_v = (const float*)d_in[4];
  const int*   mask   = (const int*)d_in[5];
  const float* Wq     = (const float*)d_in[6];
  const float* bq     = (const float*)d_in[7];
  const float* Wk     = (const float*)d_in[8];
  const float* bk     = (const float*)d_in[9];
  const float* Wv     = (const float*)d_in[10];
  const float* bv     = (const float*)d_in[11];
  const float* Wl     = (const float*)d_in[12];
  const float* bl     = (const float*)d_in[13];

  float* xout = (float*)d_out;                    // (B, Q, D)
  float* kcat = xout + 4194304;                   // (B, 4096, D)
  float* vcat = xout + 12582912;

  // ws layout: [qp / attno shared fp32 16MB][qh bf16 8MB][kh bf16 16MB][vt bf16 16MB]
  float* qp    = (float*)d_ws;                    // also attno after repack
  float* attno = qp;
  u16* qh = (u16*)(qp + 4194304);
  u16* kh = qh + 4194304;
  u16* vt = kh + 8388608;

  copy_past<<<4096, 256, 0, stream>>>(past_k, past_v, kcat, vcat);

  dim3 gg(8, 32);
  gemm_bt<<<gg, 256, 0, stream>>>(q, Wq, bq, qp,   4096, 1024, 1024, 0);
  gemm_bt<<<gg, 256, 0, stream>>>(k, Wk, bk, kcat, 4096, 1024, 1024, 1);
  gemm_bt<<<gg, 256, 0, stream>>>(v, Wv, bv, vcat, 4096, 1024, 1024, 1);

  repack_h<<<2048, 256, 0, stream>>>(qp,   qh, 2048, 11);
  repack_h<<<4096, 256, 0, stream>>>(kcat, kh, 4096, 12);
  repack_vt<<<dim3(64, 32), 256, 0, stream>>>(vcat, vt);

  attn_mfma<<<dim3(32, 32), 256, 0, stream>>>(qh, kh, vt, mask, attno);

  gemm_bt<<<gg, 256, 0, stream>>>(attno, Wl, bl, xout, 4096, 1024, 1024, 0);
}

// Round 3
// 464.498 us; speedup vs baseline: 14.3009x; 1.0850x over previous
//
#include <hip/hip_runtime.h>

#define QLEN 2048
#define KVTOT 4096
#define DMODEL 1024
#define NHEAD 16
#define HDIM 64

typedef __attribute__((ext_vector_type(8))) short bf16x8;
typedef __attribute__((ext_vector_type(4))) float f32x4;
typedef unsigned short u16;
typedef unsigned long long u64;

__device__ __forceinline__ u16 f2b(float f) {
  union { float f; unsigned u; } v; v.f = f;
  unsigned r = v.u + 0x7FFFu + ((v.u >> 16) & 1u);
  return (u16)(r >> 16);
}

__device__ __forceinline__ unsigned cvt_pk_bf16(float lo, float hi) {
  unsigned r;
  asm("v_cvt_pk_bf16_f32 %0, %1, %2" : "=v"(r) : "v"(lo), "v"(hi));
  return r;
}

// ---------------------------------------------------------------------------
// Copy past_k/past_v (B,2048,1024) into k_cat/v_cat (B,4096,1024) rows 0..2047
// ---------------------------------------------------------------------------
__global__ __launch_bounds__(256) void copy_past(
    const float* __restrict__ pk, const float* __restrict__ pv,
    float* __restrict__ kcat, float* __restrict__ vcat) {
  int i = blockIdx.x * 256 + threadIdx.x;
  int b = i >> 19;
  int r = i & 524287;
  size_t src = (size_t)i * 4;
  size_t dst = ((size_t)b * 1048576 + r) * 4;
  *(float4*)&kcat[dst] = *(const float4*)&pk[src];
  *(float4*)&vcat[dst] = *(const float4*)&pv[src];
}

// ---------------------------------------------------------------------------
// mask int32 (B,Q,4096) -> bits u64 (B,Q,64). One wave per u64 word.
// ---------------------------------------------------------------------------
__global__ __launch_bounds__(256) void maskpack(
    const int* __restrict__ mask, u64* __restrict__ bits) {
  int w = blockIdx.x * 4 + (threadIdx.x >> 6);
  int lane = threadIdx.x & 63;
  int mv = mask[(size_t)w * 64 + lane];
  u64 b = __ballot(mv != 0);
  if (lane == 0) bits[w] = b;
}

// ---------------------------------------------------------------------------
// C = A(M,K) * W(N,K)^T + bias, bf16 MFMA 16x16x32, 128x128 tile, BK=32.
// mode 0: C row = row. mode 1: row -> b*4096 + 2048 + s (cat layout).
// ---------------------------------------------------------------------------
__global__ __launch_bounds__(256) void gemm_bt(
    const float* __restrict__ A, const float* __restrict__ W,
    const float* __restrict__ bias, float* __restrict__ C,
    int M, int N, int K, int mode) {
  __shared__ u16 As[128][40];
  __shared__ u16 Bs[128][40];
  const int t = threadIdx.x;
  const int m0 = blockIdx.y * 128;
  const int n0 = blockIdx.x * 128;
  const int lane = t & 63;
  const int wid = t >> 6;
  const int wr = (wid >> 1) * 64;
  const int wc = (wid & 1) * 64;
  const int lr = lane & 15;
  const int ko = (lane >> 4) * 8;

  f32x4 acc[4][4];
  #pragma unroll
  for (int m = 0; m < 4; ++m)
    #pragma unroll
    for (int n = 0; n < 4; ++n)
      acc[m][n] = (f32x4){0.f, 0.f, 0.f, 0.f};

  for (int k0 = 0; k0 < K; k0 += 32) {
    __syncthreads();
    #pragma unroll
    for (int j = 0; j < 4; ++j) {
      int idx = t + j * 256;
      int r = idx >> 3;
      int c4 = (idx & 7) * 4;
      float4 va = *(const float4*)&A[(size_t)(m0 + r) * K + k0 + c4];
      As[r][c4 + 0] = f2b(va.x); As[r][c4 + 1] = f2b(va.y);
      As[r][c4 + 2] = f2b(va.z); As[r][c4 + 3] = f2b(va.w);
      float4 vb = *(const float4*)&W[(size_t)(n0 + r) * K + k0 + c4];
      Bs[r][c4 + 0] = f2b(vb.x); Bs[r][c4 + 1] = f2b(vb.y);
      Bs[r][c4 + 2] = f2b(vb.z); Bs[r][c4 + 3] = f2b(vb.w);
    }
    __syncthreads();
    bf16x8 av[4], bv[4];
    #pragma unroll
    for (int m = 0; m < 4; ++m)
      av[m] = *(const bf16x8*)&As[wr + m * 16 + lr][ko];
    #pragma unroll
    for (int n = 0; n < 4; ++n)
      bv[n] = *(const bf16x8*)&Bs[wc + n * 16 + lr][ko];
    #pragma unroll
    for (int m = 0; m < 4; ++m)
      #pragma unroll
      for (int n = 0; n < 4; ++n)
        acc[m][n] = __builtin_amdgcn_mfma_f32_16x16x32_bf16(av[m], bv[n], acc[m][n], 0, 0, 0);
  }

  const int rq = ((lane >> 4)) * 4;
  const int cl = lane & 15;
  #pragma unroll
  for (int m = 0; m < 4; ++m) {
    #pragma unroll
    for (int r = 0; r < 4; ++r) {
      int row = m0 + wr + m * 16 + rq + r;
      size_t orow;
      if (mode == 0) {
        orow = (size_t)row;
      } else {
        int b = row >> 11, s = row & 2047;
        orow = (size_t)(b * 4096 + 2048 + s);
      }
      float* cp = C + orow * (size_t)N;
      #pragma unroll
      for (int n = 0; n < 4; ++n) {
        int col = n0 + wc + n * 16 + cl;
        cp[col] = acc[m][n][r] + bias[col];
      }
    }
  }
}

// ---------------------------------------------------------------------------
// Same GEMM but A is bf16 (attn output); W fp32. mode 0 epilogue only.
// ---------------------------------------------------------------------------
__global__ __launch_bounds__(256) void gemm_bfA(
    const u16* __restrict__ A, const float* __restrict__ W,
    const float* __restrict__ bias, float* __restrict__ C,
    int M, int N, int K) {
  __shared__ u16 As[128][40];
  __shared__ u16 Bs[128][40];
  const int t = threadIdx.x;
  const int m0 = blockIdx.y * 128;
  const int n0 = blockIdx.x * 128;
  const int lane = t & 63;
  const int wid = t >> 6;
  const int wr = (wid >> 1) * 64;
  const int wc = (wid & 1) * 64;
  const int lr = lane & 15;
  const int ko = (lane >> 4) * 8;

  f32x4 acc[4][4];
  #pragma unroll
  for (int m = 0; m < 4; ++m)
    #pragma unroll
    for (int n = 0; n < 4; ++n)
      acc[m][n] = (f32x4){0.f, 0.f, 0.f, 0.f};

  for (int k0 = 0; k0 < K; k0 += 32) {
    __syncthreads();
    #pragma unroll
    for (int j = 0; j < 2; ++j) {
      int idx = t + j * 256;
      int r = idx >> 2;
      int c8 = (idx & 3) * 8;
      *(bf16x8*)&As[r][c8] = *(const bf16x8*)&A[(size_t)(m0 + r) * K + k0 + c8];
    }
    #pragma unroll
    for (int j = 0; j < 4; ++j) {
      int idx = t + j * 256;
      int r = idx >> 3;
      int c4 = (idx & 7) * 4;
      float4 vb = *(const float4*)&W[(size_t)(n0 + r) * K + k0 + c4];
      Bs[r][c4 + 0] = f2b(vb.x); Bs[r][c4 + 1] = f2b(vb.y);
      Bs[r][c4 + 2] = f2b(vb.z); Bs[r][c4 + 3] = f2b(vb.w);
    }
    __syncthreads();
    bf16x8 av[4], bv[4];
    #pragma unroll
    for (int m = 0; m < 4; ++m)
      av[m] = *(const bf16x8*)&As[wr + m * 16 + lr][ko];
    #pragma unroll
    for (int n = 0; n < 4; ++n)
      bv[n] = *(const bf16x8*)&Bs[wc + n * 16 + lr][ko];
    #pragma unroll
    for (int m = 0; m < 4; ++m)
      #pragma unroll
      for (int n = 0; n < 4; ++n)
        acc[m][n] = __builtin_amdgcn_mfma_f32_16x16x32_bf16(av[m], bv[n], acc[m][n], 0, 0, 0);
  }

  const int rq = (lane >> 4) * 4;
  const int cl = lane & 15;
  #pragma unroll
  for (int m = 0; m < 4; ++m) {
    #pragma unroll
    for (int r = 0; r < 4; ++r) {
      int row = m0 + wr + m * 16 + rq + r;
      float* cp = C + (size_t)row * N;
      #pragma unroll
      for (int n = 0; n < 4; ++n) {
        int col = n0 + wc + n * 16 + cl;
        cp[col] = acc[m][n][r] + bias[col];
      }
    }
  }
}

// ---------------------------------------------------------------------------
// repack fp32 [B][S][1024] -> bf16 head layout [B][16][S][64]
// ---------------------------------------------------------------------------
__global__ __launch_bounds__(256) void repack_h(
    const float* __restrict__ src, u16* __restrict__ dst, int S, int sshift) {
  int idx = blockIdx.x * 256 + threadIdx.x;
  int d8 = (idx & 7) * 8;
  int h = (idx >> 3) & 15;
  int bs = idx >> 7;
  int s = bs & (S - 1);
  int b = bs >> sshift;
  const float* sp = src + (size_t)bs * 1024 + h * 64 + d8;
  float4 a = *(const float4*)sp;
  float4 c = *(const float4*)(sp + 4);
  bf16x8 o;
  o[0] = (short)f2b(a.x); o[1] = (short)f2b(a.y); o[2] = (short)f2b(a.z); o[3] = (short)f2b(a.w);
  o[4] = (short)f2b(c.x); o[5] = (short)f2b(c.y); o[6] = (short)f2b(c.z); o[7] = (short)f2b(c.w);
  *(bf16x8*)(dst + ((size_t)(b * 16 + h) * S + s) * 64 + d8) = o;
}

// ---------------------------------------------------------------------------
// repack fp32 vcat [B][4096][1024] -> bf16 transposed [B][16][64][4096]
// ---------------------------------------------------------------------------
__global__ __launch_bounds__(256) void repack_vt(
    const float* __restrict__ src, u16* __restrict__ dst) {
  __shared__ u16 T[64][72];
  const int t = threadIdx.x;
  const int kv0 = blockIdx.x * 64;
  const int bh = blockIdx.y;
  const int b = bh >> 4, h = bh & 15;
  #pragma unroll
  for (int it = 0; it < 4; ++it) {
    int idx = t + it * 256;
    int r = idx >> 4;
    int c4 = (idx & 15) * 4;
    float4 v = *(const float4*)(src + (size_t)(b * KVTOT + kv0 + r) * DMODEL + h * 64 + c4);
    T[r][c4 + 0] = f2b(v.x); T[r][c4 + 1] = f2b(v.y);
    T[r][c4 + 2] = f2b(v.z); T[r][c4 + 3] = f2b(v.w);
  }
  __syncthreads();
  #pragma unroll
  for (int it = 0; it < 2; ++it) {
    int idx = t + it * 256;
    int d = idx & 63;
    int kc8 = (idx >> 6) * 8;
    bf16x8 o;
    #pragma unroll
    for (int j = 0; j < 8; ++j) o[j] = (short)T[kc8 + j][d];
    *(bf16x8*)(dst + (size_t)((b * 16 + h) * 64 + d) * KVTOT + kv0 + kc8) = o;
  }
}

// ---------------------------------------------------------------------------
// MFMA flash attention v3: swapped QK^T (S^T = K*Q), per-lane-row softmax,
// bitpacked mask, cvt_pk P-pack, bf16 output.
// ---------------------------------------------------------------------------
__global__ __launch_bounds__(256) void attn_mfma(
    const u16* __restrict__ qh, const u16* __restrict__ kh,
    const u16* __restrict__ vt, const u64* __restrict__ mbits,
    u16* __restrict__ out) {
  __shared__ u16 Kl[64][72];
  __shared__ u16 Vl[64][72];
  __shared__ u16 Pl[4][16][72];
  const int t = threadIdx.x;
  const int wid = t >> 6, lane = t & 63;
  const int lr = lane & 15, lg = lane >> 4;
  const int bh = blockIdx.y, b = bh >> 4, h = bh & 15;
  const int q0 = blockIdx.x * 64;
  const int qw = q0 + wid * 16;

  // Q fragment (B-operand: col=q=lr, k=dk=lg*8+j)
  bf16x8 qf[2];
  {
    const u16* qp = qh + ((size_t)bh * QLEN + qw + lr) * 64 + lg * 8;
    qf[0] = *(const bf16x8*)qp;
    qf[1] = *(const bf16x8*)(qp + 32);
  }

  const size_t khb = (size_t)bh * KVTOT * 64;
  const size_t vtb = (size_t)bh * 64 * KVTOT;
  const u64* mrow = mbits + ((size_t)b * QLEN + qw + lr) * (KVTOT / 64);

  float mprev = -1e30f, lsum = 0.f;
  f32x4 oacc[4];
  #pragma unroll
  for (int dt = 0; dt < 4; ++dt) oacc[dt] = (f32x4){0.f, 0.f, 0.f, 0.f};

  for (int it = 0; it < KVTOT / 64; ++it) {
    const int t0 = it * 64;
    __syncthreads();
    #pragma unroll
    for (int j = 0; j < 2; ++j) {
      int idx = t + j * 256;
      int r = idx >> 3, c8 = (idx & 7) * 8;
      *(bf16x8*)&Kl[r][c8] = *(const bf16x8*)(kh + khb + (size_t)(t0 + r) * 64 + c8);
      *(bf16x8*)&Vl[r][c8] = *(const bf16x8*)(vt + vtb + (size_t)r * KVTOT + t0 + c8);
    }
    __syncthreads();

    u64 mb = mrow[it];

    // S^T = K * Q : D[kv][q], col=q=lr, row kv = tile*16 + lg*4 + reg
    f32x4 sacc[4];
    #pragma unroll
    for (int tile = 0; tile < 4; ++tile) sacc[tile] = (f32x4){0.f, 0.f, 0.f, 0.f};
    #pragma unroll
    for (int tile = 0; tile < 4; ++tile) {
      bf16x8 kf0 = *(const bf16x8*)&Kl[tile * 16 + lr][lg * 8];
      bf16x8 kf1 = *(const bf16x8*)&Kl[tile * 16 + lr][32 + lg * 8];
      sacc[tile] = __builtin_amdgcn_mfma_f32_16x16x32_bf16(kf0, qf[0], sacc[tile], 0, 0, 0);
      sacc[tile] = __builtin_amdgcn_mfma_f32_16x16x32_bf16(kf1, qf[1], sacc[tile], 0, 0, 0);
    }

    // scale + mask + row max (this lane owns q = qw + lr)
    float sv[4][4];
    float rmax = -1e30f;
    #pragma unroll
    for (int tile = 0; tile < 4; ++tile)
      #pragma unroll
      for (int r = 0; r < 4; ++r) {
        int bitidx = tile * 16 + lg * 4 + r;
        float mterm = ((mb >> bitidx) & 1ull) ? -10000.f : 0.f;
        sv[tile][r] = sacc[tile][r] * 0.125f + mterm;
        rmax = fmaxf(rmax, sv[tile][r]);
      }
    rmax = fmaxf(rmax, __shfl_xor(rmax, 16));
    rmax = fmaxf(rmax, __shfl_xor(rmax, 32));
    float mnew = fmaxf(mprev, rmax);
    float corr = __expf(mprev - mnew);
    mprev = mnew;

    // P = exp(sv - mnew); pack pairs along kv, store to Pl[q][kv]
    float rsum = 0.f;
    #pragma unroll
    for (int tile = 0; tile < 4; ++tile) {
      float p0 = __expf(sv[tile][0] - mnew);
      float p1 = __expf(sv[tile][1] - mnew);
      float p2 = __expf(sv[tile][2] - mnew);
      float p3 = __expf(sv[tile][3] - mnew);
      rsum += (p0 + p1) + (p2 + p3);
      unsigned w0 = cvt_pk_bf16(p0, p1);
      unsigned w1 = cvt_pk_bf16(p2, p3);
      uint2 w = make_uint2(w0, w1);
      *(uint2*)&Pl[wid][lr][tile * 16 + lg * 4] = w;
    }
    rsum += __shfl_xor(rsum, 16);
    rsum += __shfl_xor(rsum, 32);
    lsum = lsum * corr + rsum;

    // rescale O accumulator: corr for q = lg*4 + r lives at lane (lg*4+r)
    float cr[4];
    #pragma unroll
    for (int r = 0; r < 4; ++r) cr[r] = __shfl(corr, lg * 4 + r);
    #pragma unroll
    for (int dt = 0; dt < 4; ++dt)
      #pragma unroll
      for (int r = 0; r < 4; ++r) oacc[dt][r] *= cr[r];

    // PV: O[q][d] += P[q][kv] * V[kv][d]
    bf16x8 pa0 = *(const bf16x8*)&Pl[wid][lr][lg * 8];
    bf16x8 pa1 = *(const bf16x8*)&Pl[wid][lr][32 + lg * 8];
    #pragma unroll
    for (int dt = 0; dt < 4; ++dt) {
      bf16x8 vb0 = *(const bf16x8*)&Vl[dt * 16 + lr][lg * 8];
      bf16x8 vb1 = *(const bf16x8*)&Vl[dt * 16 + lr][32 + lg * 8];
      oacc[dt] = __builtin_amdgcn_mfma_f32_16x16x32_bf16(pa0, vb0, oacc[dt], 0, 0, 0);
      oacc[dt] = __builtin_amdgcn_mfma_f32_16x16x32_bf16(pa1, vb1, oacc[dt], 0, 0, 0);
    }
  }

  float inv = 1.f / lsum;   // for q = qw + lr
  float ivr[4];
  #pragma unroll
  for (int r = 0; r < 4; ++r) ivr[r] = __shfl(inv, lg * 4 + r);
  #pragma unroll
  for (int dt = 0; dt < 4; ++dt)
    #pragma unroll
    for (int r = 0; r < 4; ++r)
      out[((size_t)b * QLEN + qw + lg * 4 + r) * DMODEL + h * 64 + dt * 16 + lr] =
          f2b(oacc[dt][r] * ivr[r]);
}

// ---------------------------------------------------------------------------
extern "C" void kernel_launch(void* const* d_in, const int* in_sizes, int n_in,
                              void* d_out, int out_size, void* d_ws, size_t ws_size,
                              hipStream_t stream) {
  const float* q      = (const float*)d_in[0];
  const float* k      = (const float*)d_in[1];
  const float* v      = (const float*)d_in[2];
  const float* past_k = (const float*)d_in[3];
  const float* past_v = (const float*)d_in[4];
  const int*   mask   = (const int*)d_in[5];
  const float* Wq     = (const float*)d_in[6];
  const float* bq     = (const float*)d_in[7];
  const float* Wk     = (const float*)d_in[8];
  const float* bk     = (const float*)d_in[9];
  const float* Wv     = (const float*)d_in[10];
  const float* bv     = (const float*)d_in[11];
  const float* Wl     = (const float*)d_in[12];
  const float* bl     = (const float*)d_in[13];

  float* xout = (float*)d_out;                    // (B, Q, D)
  float* kcat = xout + 4194304;                   // (B, 4096, D)
  float* vcat = xout + 12582912;

  // ws: [qp fp32 16MB (reused as attno_bf)][qh 8MB][kh 16MB][vt 16MB][mbits 2MB]
  float* qp = (float*)d_ws;
  u16* attno_bf = (u16*)d_ws;
  u16* qh = (u16*)(qp + 4194304);
  u16* kh = qh + 4194304;
  u16* vt = kh + 8388608;
  u64* mbits = (u64*)(vt + 8388608);

  copy_past<<<4096, 256, 0, stream>>>(past_k, past_v, kcat, vcat);
  maskpack<<<65536, 256, 0, stream>>>(mask, mbits);

  dim3 gg(8, 32);
  gemm_bt<<<gg, 256, 0, stream>>>(q, Wq, bq, qp,   4096, 1024, 1024, 0);
  gemm_bt<<<gg, 256, 0, stream>>>(k, Wk, bk, kcat, 4096, 1024, 1024, 1);
  gemm_bt<<<gg, 256, 0, stream>>>(v, Wv, bv, vcat, 4096, 1024, 1024, 1);

  repack_h<<<2048, 256, 0, stream>>>(qp,   qh, 2048, 11);
  repack_h<<<4096, 256, 0, stream>>>(kcat, kh, 4096, 12);
  repack_vt<<<dim3(64, 32), 256, 0, stream>>>(vcat, vt);

  attn_mfma<<<dim3(32, 32), 256, 0, stream>>>(qh, kh, vt, mbits, attno_bf);

  gemm_bfA<<<gg, 256, 0, stream>>>(attno_bf, Wl, bl, xout, 4096, 1024, 1024);
}

// Round 4
// 434.323 us; speedup vs baseline: 15.2945x; 1.0695x over previous
//
#include <hip/hip_runtime.h>

#define QLEN 2048
#define KVTOT 4096
#define DMODEL 1024
#define NHEAD 16
#define HDIM 64
#define MASKC -10000.0f
#define SENT  -20000.0f

typedef __attribute__((ext_vector_type(8))) short bf16x8;
typedef __attribute__((ext_vector_type(4))) float f32x4;
typedef unsigned short u16;
typedef unsigned long long u64;

__device__ __forceinline__ u16 f2b(float f) {
  union { float f; unsigned u; } v; v.f = f;
  unsigned r = v.u + 0x7FFFu + ((v.u >> 16) & 1u);
  return (u16)(r >> 16);
}

__device__ __forceinline__ unsigned cvt_pk_bf16(float lo, float hi) {
  unsigned r;
  asm("v_cvt_pk_bf16_f32 %0, %1, %2" : "=v"(r) : "v"(lo), "v"(hi));
  return r;
}

// ---------------------------------------------------------------------------
// past_k/past_v fp32 -> k_cat/v_cat rows 0..2047, plus kh bf16 head layout.
// ---------------------------------------------------------------------------
__global__ __launch_bounds__(256) void copy_past(
    const float* __restrict__ pk, const float* __restrict__ pv,
    float* __restrict__ kcat, float* __restrict__ vcat,
    u16* __restrict__ kh) {
  int i = blockIdx.x * 256 + threadIdx.x;        // float4 units
  int b = i >> 19;
  int r = i & 524287;                            // within-batch float4 idx
  size_t src = (size_t)i * 4;
  size_t dst = ((size_t)b * 1048576 + r) * 4;
  float4 kk = *(const float4*)&pk[src];
  float4 vv = *(const float4*)&pv[src];
  *(float4*)&kcat[dst] = kk;
  *(float4*)&vcat[dst] = vv;
  // kh: [b][h][4096][64], past rows s = 0..2047
  int s = r >> 8;                                // row 0..2047
  int c4 = (r & 255) * 4;                        // col 0..1020
  int h = c4 >> 6, d = c4 & 63;
  uint2 w = make_uint2(cvt_pk_bf16(kk.x, kk.y), cvt_pk_bf16(kk.z, kk.w));
  *(uint2*)&kh[((size_t)(b * 16 + h) * KVTOT + s) * 64 + d] = w;
}

// ---------------------------------------------------------------------------
// mask int32 (B,Q,4096) -> bits u64 (B,Q,64)
// ---------------------------------------------------------------------------
__global__ __launch_bounds__(256) void maskpack(
    const int* __restrict__ mask, u64* __restrict__ bits) {
  int w = blockIdx.x * 4 + (threadIdx.x >> 6);
  int lane = threadIdx.x & 63;
  int mv = mask[(size_t)w * 64 + lane];
  u64 b = __ballot(mv != 0);
  if (lane == 0) bits[w] = b;
}

// ---------------------------------------------------------------------------
// C = A(M,1024) * W(1024,1024)^T + bias. fp32 A staged via cvt_pk.
// Optional fp32 out Cf (cat or plain rows), optional bf16 head-layout out Hh.
// ---------------------------------------------------------------------------
__global__ __launch_bounds__(256) void gemm_bt(
    const float* __restrict__ A, const float* __restrict__ W,
    const float* __restrict__ bias, float* __restrict__ Cf,
    u16* __restrict__ Hh, int cat, float hscale) {
  const int N = 1024, K = 1024;
  __shared__ u16 As[128][40];
  __shared__ u16 Bs[128][40];
  const int t = threadIdx.x;
  const int m0 = blockIdx.y * 128;
  const int n0 = blockIdx.x * 128;
  const int lane = t & 63;
  const int wid = t >> 6;
  const int wr = (wid >> 1) * 64;
  const int wc = (wid & 1) * 64;
  const int lr = lane & 15;
  const int ko = (lane >> 4) * 8;

  f32x4 acc[4][4];
  #pragma unroll
  for (int m = 0; m < 4; ++m)
    #pragma unroll
    for (int n = 0; n < 4; ++n)
      acc[m][n] = (f32x4){0.f, 0.f, 0.f, 0.f};

  for (int k0 = 0; k0 < K; k0 += 32) {
    __syncthreads();
    #pragma unroll
    for (int j = 0; j < 4; ++j) {
      int idx = t + j * 256;
      int r = idx >> 3;
      int c4 = (idx & 7) * 4;
      float4 va = *(const float4*)&A[(size_t)(m0 + r) * K + k0 + c4];
      *(uint2*)&As[r][c4] = make_uint2(cvt_pk_bf16(va.x, va.y), cvt_pk_bf16(va.z, va.w));
      float4 vb = *(const float4*)&W[(size_t)(n0 + r) * K + k0 + c4];
      *(uint2*)&Bs[r][c4] = make_uint2(cvt_pk_bf16(vb.x, vb.y), cvt_pk_bf16(vb.z, vb.w));
    }
    __syncthreads();
    bf16x8 av[4], bv[4];
    #pragma unroll
    for (int m = 0; m < 4; ++m)
      av[m] = *(const bf16x8*)&As[wr + m * 16 + lr][ko];
    #pragma unroll
    for (int n = 0; n < 4; ++n)
      bv[n] = *(const bf16x8*)&Bs[wc + n * 16 + lr][ko];
    #pragma unroll
    for (int m = 0; m < 4; ++m)
      #pragma unroll
      for (int n = 0; n < 4; ++n)
        acc[m][n] = __builtin_amdgcn_mfma_f32_16x16x32_bf16(av[m], bv[n], acc[m][n], 0, 0, 0);
  }

  const int rq = (lane >> 4) * 4;
  const int cl = lane & 15;
  #pragma unroll
  for (int m = 0; m < 4; ++m) {
    #pragma unroll
    for (int r = 0; r < 4; ++r) {
      int row = m0 + wr + m * 16 + rq + r;     // b*2048 + s
      int bb = row >> 11, s = row & 2047;
      float* cp = nullptr;
      if (Cf) {
        size_t orow = cat ? (size_t)(bb * 4096 + 2048 + s) : (size_t)row;
        cp = Cf + orow * N;
      }
      int srow = cat ? (2048 + s) : s;
      int Scat = cat ? 4096 : 2048;
      #pragma unroll
      for (int n = 0; n < 4; ++n) {
        int col = n0 + wc + n * 16 + cl;
        float val = acc[m][n][r] + bias[col];
        if (cp) cp[col] = val;
        if (Hh) {
          int h = col >> 6, d = col & 63;
          Hh[((size_t)(bb * 16 + h) * Scat + srow) * 64 + d] = f2b(val * hscale);
        }
      }
    }
  }
}

// ---------------------------------------------------------------------------
// Final GEMM: A bf16 (attn out), W fp32 via cvt_pk, out fp32 + bias.
// ---------------------------------------------------------------------------
__global__ __launch_bounds__(256) void gemm_bfA(
    const u16* __restrict__ A, const float* __restrict__ W,
    const float* __restrict__ bias, float* __restrict__ C) {
  const int N = 1024, K = 1024;
  __shared__ u16 As[128][40];
  __shared__ u16 Bs[128][40];
  const int t = threadIdx.x;
  const int m0 = blockIdx.y * 128;
  const int n0 = blockIdx.x * 128;
  const int lane = t & 63;
  const int wid = t >> 6;
  const int wr = (wid >> 1) * 64;
  const int wc = (wid & 1) * 64;
  const int lr = lane & 15;
  const int ko = (lane >> 4) * 8;

  f32x4 acc[4][4];
  #pragma unroll
  for (int m = 0; m < 4; ++m)
    #pragma unroll
    for (int n = 0; n < 4; ++n)
      acc[m][n] = (f32x4){0.f, 0.f, 0.f, 0.f};

  for (int k0 = 0; k0 < K; k0 += 32) {
    __syncthreads();
    #pragma unroll
    for (int j = 0; j < 2; ++j) {
      int idx = t + j * 256;
      int r = idx >> 2;
      int c8 = (idx & 3) * 8;
      *(bf16x8*)&As[r][c8] = *(const bf16x8*)&A[(size_t)(m0 + r) * K + k0 + c8];
    }
    #pragma unroll
    for (int j = 0; j < 4; ++j) {
      int idx = t + j * 256;
      int r = idx >> 3;
      int c4 = (idx & 7) * 4;
      float4 vb = *(const float4*)&W[(size_t)(n0 + r) * K + k0 + c4];
      *(uint2*)&Bs[r][c4] = make_uint2(cvt_pk_bf16(vb.x, vb.y), cvt_pk_bf16(vb.z, vb.w));
    }
    __syncthreads();
    bf16x8 av[4], bv[4];
    #pragma unroll
    for (int m = 0; m < 4; ++m)
      av[m] = *(const bf16x8*)&As[wr + m * 16 + lr][ko];
    #pragma unroll
    for (int n = 0; n < 4; ++n)
      bv[n] = *(const bf16x8*)&Bs[wc + n * 16 + lr][ko];
    #pragma unroll
    for (int m = 0; m < 4; ++m)
      #pragma unroll
      for (int n = 0; n < 4; ++n)
        acc[m][n] = __builtin_amdgcn_mfma_f32_16x16x32_bf16(av[m], bv[n], acc[m][n], 0, 0, 0);
  }

  const int rq = (lane >> 4) * 4;
  const int cl = lane & 15;
  #pragma unroll
  for (int m = 0; m < 4; ++m) {
    #pragma unroll
    for (int r = 0; r < 4; ++r) {
      int row = m0 + wr + m * 16 + rq + r;
      float* cp = C + (size_t)row * N;
      #pragma unroll
      for (int n = 0; n < 4; ++n) {
        int col = n0 + wc + n * 16 + cl;
        cp[col] = acc[m][n][r] + bias[col];
      }
    }
  }
}

// ---------------------------------------------------------------------------
// vcat fp32 [B][4096][1024] -> bf16 transposed [B][16][64][4096]
// ---------------------------------------------------------------------------
__global__ __launch_bounds__(256) void repack_vt(
    const float* __restrict__ src, u16* __restrict__ dst) {
  __shared__ u16 T[64][72];
  const int t = threadIdx.x;
  const int kv0 = blockIdx.x * 64;
  const int bh = blockIdx.y;
  const int b = bh >> 4, h = bh & 15;
  #pragma unroll
  for (int it = 0; it < 4; ++it) {
    int idx = t + it * 256;
    int r = idx >> 4;
    int c4 = (idx & 15) * 4;
    float4 v = *(const float4*)(src + (size_t)(b * KVTOT + kv0 + r) * DMODEL + h * 64 + c4);
    *(uint2*)&T[r][c4] = make_uint2(cvt_pk_bf16(v.x, v.y), cvt_pk_bf16(v.z, v.w));
  }
  __syncthreads();
  #pragma unroll
  for (int it = 0; it < 2; ++it) {
    int idx = t + it * 256;
    int d = idx & 63;
    int kc8 = (idx >> 6) * 8;
    bf16x8 o;
    #pragma unroll
    for (int j = 0; j < 8; ++j) o[j] = (short)T[kc8 + j][d];
    *(bf16x8*)(dst + (size_t)((b * 16 + h) * 64 + d) * KVTOT + kv0 + kc8) = o;
  }
}

// ---------------------------------------------------------------------------
// MFMA flash attention v4: mask+max folded into MFMA C-init, ones-column
// lsum, defer-max, reg-prefetched K/V staging, XCD-chunked swizzle.
// ---------------------------------------------------------------------------
__global__ __launch_bounds__(256) void attn_mfma(
    const u16* __restrict__ qh, const u16* __restrict__ kh,
    const u16* __restrict__ vt, const u64* __restrict__ mbits,
    u16* __restrict__ out) {
  __shared__ u16 Kl[64][72];
  __shared__ u16 Vl[80][72];        // rows 64..79 = 1.0 (lsum column tile)
  __shared__ u16 Pl[4][16][72];
  const int t = threadIdx.x;
  const int wid = t >> 6, lane = t & 63;
  const int lr = lane & 15, lg = lane >> 4;
  // XCD swizzle: each XCD owns 4 consecutive bh (K/V fits 4MB L2)
  const int fid = blockIdx.x;                      // 0..1023
  const int virt = (fid & 7) * 128 + (fid >> 3);
  const int bh = virt >> 5, qt = virt & 31;
  const int b = bh >> 4, h = bh & 15;
  const int qw = qt * 64 + wid * 16;

  // ones rows for lsum tile (written once; first loop barrier publishes)
  {
    int r = 64 + (t >> 4), c = (t & 15) * 4;
    *(uint2*)&Vl[r][c] = make_uint2(0x3F803F80u, 0x3F803F80u);
  }

  bf16x8 qf[2];
  {
    const u16* qp = qh + ((size_t)bh * QLEN + qw + lr) * 64 + lg * 8;
    qf[0] = *(const bf16x8*)qp;
    qf[1] = *(const bf16x8*)(qp + 32);
  }

  const size_t khb = (size_t)bh * KVTOT * 64;
  const size_t vtb = (size_t)bh * 64 * KVTOT;
  const u64* mrow = mbits + ((size_t)b * QLEN + qw + lr) * (KVTOT / 64);

  // prefetch tile 0 into regs
  bf16x8 kreg[2], vreg[2];
  #pragma unroll
  for (int j = 0; j < 2; ++j) {
    int idx = t + j * 256;
    int r = idx >> 3, c8 = (idx & 7) * 8;
    kreg[j] = *(const bf16x8*)(kh + khb + (size_t)r * 64 + c8);
    vreg[j] = *(const bf16x8*)(vt + vtb + (size_t)r * KVTOT + c8);
  }

  float mprev = SENT;
  f32x4 oacc[5];
  #pragma unroll
  for (int dt = 0; dt < 5; ++dt) oacc[dt] = (f32x4){0.f, 0.f, 0.f, 0.f};

  for (int it = 0; it < KVTOT / 64; ++it) {
    u64 mb = mrow[it];
    __syncthreads();
    #pragma unroll
    for (int j = 0; j < 2; ++j) {
      int idx = t + j * 256;
      int r = idx >> 3, c8 = (idx & 7) * 8;
      *(bf16x8*)&Kl[r][c8] = kreg[j];
      *(bf16x8*)&Vl[r][c8] = vreg[j];
    }
    __syncthreads();
    if (it + 1 < KVTOT / 64) {
      int t0n = (it + 1) * 64;
      #pragma unroll
      for (int j = 0; j < 2; ++j) {
        int idx = t + j * 256;
        int r = idx >> 3, c8 = (idx & 7) * 8;
        kreg[j] = *(const bf16x8*)(kh + khb + (size_t)(t0n + r) * 64 + c8);
        vreg[j] = *(const bf16x8*)(vt + vtb + (size_t)r * KVTOT + t0n + c8);
      }
    }

    // QK^T with C-init = mask - mprev  (D[kv][q], col=q=lr, row kv=tile*16+lg*4+r)
    const u64 mq = mb >> (lg * 4);
    const float negm = -mprev, negmm = MASKC - mprev;
    f32x4 sacc[4];
    #pragma unroll
    for (int tile = 0; tile < 4; ++tile) {
      unsigned nib = (unsigned)((mq >> (tile * 16)) & 0xFull);
      #pragma unroll
      for (int r = 0; r < 4; ++r)
        sacc[tile][r] = (nib & (1u << r)) ? negmm : negm;
      bf16x8 kf0 = *(const bf16x8*)&Kl[tile * 16 + lr][lg * 8];
      bf16x8 kf1 = *(const bf16x8*)&Kl[tile * 16 + lr][32 + lg * 8];
      sacc[tile] = __builtin_amdgcn_mfma_f32_16x16x32_bf16(kf0, qf[0], sacc[tile], 0, 0, 0);
      sacc[tile] = __builtin_amdgcn_mfma_f32_16x16x32_bf16(kf1, qf[1], sacc[tile], 0, 0, 0);
    }

    // row max in shifted domain (this lane owns q = qw + lr)
    float rmax = fmaxf(fmaxf(fmaxf(sacc[0][0], sacc[0][1]), fmaxf(sacc[0][2], sacc[0][3])),
                       fmaxf(fmaxf(sacc[1][0], sacc[1][1]), fmaxf(sacc[1][2], sacc[1][3])));
    rmax = fmaxf(rmax, fmaxf(fmaxf(fmaxf(sacc[2][0], sacc[2][1]), fmaxf(sacc[2][2], sacc[2][3])),
                             fmaxf(fmaxf(sacc[3][0], sacc[3][1]), fmaxf(sacc[3][2], sacc[3][3]))));
    rmax = fmaxf(rmax, __shfl_xor(rmax, 16));
    rmax = fmaxf(rmax, __shfl_xor(rmax, 32));

    if (__all(rmax <= 8.0f)) {
      // deferred: no rescale, exp of shifted scores directly
      #pragma unroll
      for (int tile = 0; tile < 4; ++tile) {
        float p0 = __expf(sacc[tile][0]);
        float p1 = __expf(sacc[tile][1]);
        float p2 = __expf(sacc[tile][2]);
        float p3 = __expf(sacc[tile][3]);
        *(uint2*)&Pl[wid][lr][tile * 16 + lg * 4] =
            make_uint2(cvt_pk_bf16(p0, p1), cvt_pk_bf16(p2, p3));
      }
    } else {
      float shift = fmaxf(rmax, 0.f);
      float corr = __expf(-shift);
      float cr[4];
      #pragma unroll
      for (int r = 0; r < 4; ++r) cr[r] = __shfl(corr, lg * 4 + r);
      #pragma unroll
      for (int dt = 0; dt < 5; ++dt)
        #pragma unroll
        for (int r = 0; r < 4; ++r) oacc[dt][r] *= cr[r];
      mprev += shift;
      #pragma unroll
      for (int tile = 0; tile < 4; ++tile) {
        float p0 = __expf(sacc[tile][0] - shift);
        float p1 = __expf(sacc[tile][1] - shift);
        float p2 = __expf(sacc[tile][2] - shift);
        float p3 = __expf(sacc[tile][3] - shift);
        *(uint2*)&Pl[wid][lr][tile * 16 + lg * 4] =
            make_uint2(cvt_pk_bf16(p0, p1), cvt_pk_bf16(p2, p3));
      }
    }

    // PV (+ lsum tile dt=4): O[q][d] += P[q][kv] * V[kv][d]
    bf16x8 pa0 = *(const bf16x8*)&Pl[wid][lr][lg * 8];
    bf16x8 pa1 = *(const bf16x8*)&Pl[wid][lr][32 + lg * 8];
    #pragma unroll
    for (int dt = 0; dt < 5; ++dt) {
      bf16x8 vb0 = *(const bf16x8*)&Vl[dt * 16 + lr][lg * 8];
      bf16x8 vb1 = *(const bf16x8*)&Vl[dt * 16 + lr][32 + lg * 8];
      oacc[dt] = __builtin_amdgcn_mfma_f32_16x16x32_bf16(pa0, vb0, oacc[dt], 0, 0, 0);
      oacc[dt] = __builtin_amdgcn_mfma_f32_16x16x32_bf16(pa1, vb1, oacc[dt], 0, 0, 0);
    }
  }

  #pragma unroll
  for (int r = 0; r < 4; ++r) {
    float inv = 1.f / oacc[4][r];           // lsum for q = qw + lg*4 + r
    #pragma unroll
    for (int dt = 0; dt < 4; ++dt)
      out[((size_t)b * QLEN + qw + lg * 4 + r) * DMODEL + h * 64 + dt * 16 + lr] =
          f2b(oacc[dt][r] * inv);
  }
}

// ---------------------------------------------------------------------------
extern "C" void kernel_launch(void* const* d_in, const int* in_sizes, int n_in,
                              void* d_out, int out_size, void* d_ws, size_t ws_size,
                              hipStream_t stream) {
  const float* q      = (const float*)d_in[0];
  const float* k      = (const float*)d_in[1];
  const float* v      = (const float*)d_in[2];
  const float* past_k = (const float*)d_in[3];
  const float* past_v = (const float*)d_in[4];
  const int*   mask   = (const int*)d_in[5];
  const float* Wq     = (const float*)d_in[6];
  const float* bq     = (const float*)d_in[7];
  const float* Wk     = (const float*)d_in[8];
  const float* bk     = (const float*)d_in[9];
  const float* Wv     = (const float*)d_in[10];
  const float* bv     = (const float*)d_in[11];
  const float* Wl     = (const float*)d_in[12];
  const float* bl     = (const float*)d_in[13];

  float* xout = (float*)d_out;                    // (B, Q, D)
  float* kcat = xout + 4194304;                   // (B, 4096, D)
  float* vcat = xout + 12582912;

  // ws (u16 units): attno 0..4M, qh 4M..8M, kh 8M..16M, vt 16M..24M, mbits after
  u16* wsb = (u16*)d_ws;
  u16* attno_bf = wsb;                            // (B,Q,1024) bf16
  u16* qh = wsb + 4194304;                        // [B][16][2048][64]
  u16* kh = wsb + 8388608;                        // [B][16][4096][64]
  u16* vt = wsb + 16777216;                       // [B][16][64][4096]
  u64* mbits = (u64*)(wsb + 25165824);

  copy_past<<<4096, 256, 0, stream>>>(past_k, past_v, kcat, vcat, kh);
  maskpack<<<65536, 256, 0, stream>>>(mask, mbits);

  dim3 gg(8, 32);
  // Q: bf16 head layout only, pre-scaled by 1/8
  gemm_bt<<<gg, 256, 0, stream>>>(q, Wq, bq, nullptr, qh, 0, 0.125f);
  // K: fp32 cat + bf16 head layout
  gemm_bt<<<gg, 256, 0, stream>>>(k, Wk, bk, kcat, kh, 1, 1.0f);
  // V: fp32 cat only
  gemm_bt<<<gg, 256, 0, stream>>>(v, Wv, bv, vcat, nullptr, 1, 1.0f);

  repack_vt<<<dim3(64, 32), 256, 0, stream>>>(vcat, vt);

  attn_mfma<<<1024, 256, 0, stream>>>(qh, kh, vt, mbits, attno_bf);

  gemm_bfA<<<gg, 256, 0, stream>>>(attno_bf, Wl, bl, xout);
}

// Round 5
// 323.271 us; speedup vs baseline: 20.5485x; 1.3435x over previous
//
#include <hip/hip_runtime.h>

#define QLEN 2048
#define KVTOT 4096
#define DMODEL 1024
#define MASKC -10000.0f
#define SENT  -20000.0f

typedef __attribute__((ext_vector_type(8))) short bf16x8;
typedef __attribute__((ext_vector_type(4))) float f32x4;
typedef unsigned short u16;
typedef unsigned int u32;
typedef unsigned long long u64;

__device__ __forceinline__ u16 f2b(float f) {
  union { float f; unsigned u; } v; v.f = f;
  unsigned r = v.u + 0x7FFFu + ((v.u >> 16) & 1u);
  return (u16)(r >> 16);
}

__device__ __forceinline__ u32 cvt_pk_bf16(float lo, float hi) {
  u32 r;
  asm("v_cvt_pk_bf16_f32 %0, %1, %2" : "=v"(r) : "v"(lo), "v"(hi));
  return r;
}

// async global->LDS, 16B per lane; lds dest = wave-uniform base + lane*16
__device__ __forceinline__ void gll16(const u16* g, u16* l) {
  __builtin_amdgcn_global_load_lds(
      (const __attribute__((address_space(1))) u32*)g,
      (__attribute__((address_space(3))) u32*)l, 16, 0, 0);
}

// ---------------------------------------------------------------------------
// past_k/past_v fp32 -> k_cat/v_cat rows 0..2047, plus kh bf16 head layout.
// ---------------------------------------------------------------------------
__global__ __launch_bounds__(256) void copy_past(
    const float* __restrict__ pk, const float* __restrict__ pv,
    float* __restrict__ kcat, float* __restrict__ vcat,
    u16* __restrict__ kh) {
  int i = blockIdx.x * 256 + threadIdx.x;        // float4 units
  int b = i >> 19;
  int r = i & 524287;
  size_t src = (size_t)i * 4;
  size_t dst = ((size_t)b * 1048576 + r) * 4;
  float4 kk = *(const float4*)&pk[src];
  float4 vv = *(const float4*)&pv[src];
  *(float4*)&kcat[dst] = kk;
  *(float4*)&vcat[dst] = vv;
  int s = r >> 8;
  int c4 = (r & 255) * 4;
  int h = c4 >> 6, d = c4 & 63;
  uint2 w = make_uint2(cvt_pk_bf16(kk.x, kk.y), cvt_pk_bf16(kk.z, kk.w));
  *(uint2*)&kh[((size_t)(b * 16 + h) * KVTOT + s) * 64 + d] = w;
}

// ---------------------------------------------------------------------------
// mask int32 (B,Q,4096) -> bits u64 (B,Q,64)
// ---------------------------------------------------------------------------
__global__ __launch_bounds__(256) void maskpack(
    const int* __restrict__ mask, u64* __restrict__ bits) {
  int w = blockIdx.x * 4 + (threadIdx.x >> 6);
  int lane = threadIdx.x & 63;
  int mv = mask[(size_t)w * 64 + lane];
  u64 b = __ballot(mv != 0);
  if (lane == 0) bits[w] = b;
}

// ---------------------------------------------------------------------------
// Weights fp32 -> bf16, 4 matrices of 1M elems (blockIdx.y selects)
// ---------------------------------------------------------------------------
__global__ __launch_bounds__(256) void w2b(
    const float* __restrict__ w0, const float* __restrict__ w1,
    const float* __restrict__ w2, const float* __restrict__ w3,
    u16* __restrict__ dst) {
  const float* src = blockIdx.y == 0 ? w0 : blockIdx.y == 1 ? w1
                   : blockIdx.y == 2 ? w2 : w3;
  size_t i = ((size_t)blockIdx.x * 256 + threadIdx.x) * 8;
  float4 a = *(const float4*)&src[i];
  float4 b = *(const float4*)&src[i + 4];
  uint4 o = {cvt_pk_bf16(a.x, a.y), cvt_pk_bf16(a.z, a.w),
             cvt_pk_bf16(b.x, b.y), cvt_pk_bf16(b.z, b.w)};
  *(uint4*)&dst[(size_t)blockIdx.y * 1048576 + i] = o;
}

// ---------------------------------------------------------------------------
// z-fused QKV projections: C = A*W^T + bias. A fp32 (cvt staging), W bf16
// via global_load_lds. 128x128 tile, BK=32, grid (8,32,3) = 768 blocks.
// ---------------------------------------------------------------------------
__global__ __launch_bounds__(256) void gemm_qkv(
    const float* __restrict__ qA, const float* __restrict__ kA,
    const float* __restrict__ vA, const u16* __restrict__ Wb,
    const float* __restrict__ bq, const float* __restrict__ bk,
    const float* __restrict__ bv,
    u16* __restrict__ qh, float* __restrict__ kcat, u16* __restrict__ kh,
    float* __restrict__ vcat) {
  const int K = 1024, N = 1024;
  __shared__ u16 As[128][32];
  __shared__ u16 Bs[128][32];
  const int z = blockIdx.z;
  const float* A = (z == 0) ? qA : (z == 1) ? kA : vA;
  const u16* W = Wb + (size_t)z * 1048576;
  const float* bias = (z == 0) ? bq : (z == 1) ? bk : bv;
  const int t = threadIdx.x;
  const int m0 = blockIdx.y * 128, n0 = blockIdx.x * 128;
  const int lane = t & 63, wid = t >> 6;
  const int wr = (wid >> 1) * 64, wc = (wid & 1) * 64;
  const int lr = lane & 15, lg = lane >> 4;
  const int ko = lg * 8;

  f32x4 acc[4][4];
  #pragma unroll
  for (int m = 0; m < 4; ++m)
    #pragma unroll
    for (int n = 0; n < 4; ++n)
      acc[m][n] = (f32x4){0.f, 0.f, 0.f, 0.f};

  for (int k0 = 0; k0 < K; k0 += 32) {
    // A tile -> regs (overlaps previous iteration's MFMA tail)
    float4 a0[2], a1[2];
    #pragma unroll
    for (int j = 0; j < 2; ++j) {
      int idx = t + j * 256;
      int r = idx >> 2, c8 = (idx & 3) * 8;
      const float* ap = A + (size_t)(m0 + r) * K + k0 + c8;
      a0[j] = *(const float4*)ap;
      a1[j] = *(const float4*)(ap + 4);
    }
    __syncthreads();                       // prev frag reads done
    #pragma unroll
    for (int j = 0; j < 2; ++j) {
      int idx = t + j * 256;
      int r = idx >> 2, c8 = (idx & 3) * 8;
      gll16(W + (size_t)(n0 + r) * K + k0 + c8,
            &Bs[0][0] + (size_t)(j * 256 + (t & ~63)) * 8);
      uint4 o = {cvt_pk_bf16(a0[j].x, a0[j].y), cvt_pk_bf16(a0[j].z, a0[j].w),
                 cvt_pk_bf16(a1[j].x, a1[j].y), cvt_pk_bf16(a1[j].z, a1[j].w)};
      *(uint4*)&As[r][c8] = o;
    }
    __syncthreads();                       // vmcnt(0)+lgkmcnt(0) drain
    bf16x8 av[4], bv4[4];
    #pragma unroll
    for (int m = 0; m < 4; ++m)
      av[m] = *(const bf16x8*)&As[wr + m * 16 + lr][ko];
    #pragma unroll
    for (int n = 0; n < 4; ++n)
      bv4[n] = *(const bf16x8*)&Bs[wc + n * 16 + lr][ko];
    #pragma unroll
    for (int m = 0; m < 4; ++m)
      #pragma unroll
      for (int n = 0; n < 4; ++n)
        acc[m][n] = __builtin_amdgcn_mfma_f32_16x16x32_bf16(av[m], bv4[n], acc[m][n], 0, 0, 0);
  }

  const int rq = lg * 4;
  #pragma unroll
  for (int m = 0; m < 4; ++m) {
    #pragma unroll
    for (int r = 0; r < 4; ++r) {
      int row = m0 + wr + m * 16 + rq + r;     // = b*2048 + s
      int bb = row >> 11, s = row & 2047;
      #pragma unroll
      for (int n = 0; n < 4; ++n) {
        int col = n0 + wc + n * 16 + lr;
        float val = acc[m][n][r] + bias[col];
        int hh = col >> 6, d = col & 63;
        if (z == 0) {
          qh[((size_t)(bb * 16 + hh) * QLEN + s) * 64 + d] = f2b(val * 0.125f);
        } else if (z == 1) {
          kcat[(size_t)(bb * 4096 + 2048 + s) * 1024 + col] = val;
          kh[((size_t)(bb * 16 + hh) * KVTOT + 2048 + s) * 64 + d] = f2b(val);
        } else {
          vcat[(size_t)(bb * 4096 + 2048 + s) * 1024 + col] = val;
        }
      }
    }
  }
}

// ---------------------------------------------------------------------------
// Final GEMM: A bf16 (attn out), W bf16 — both via global_load_lds.
// ---------------------------------------------------------------------------
__global__ __launch_bounds__(256) void gemm_out(
    const u16* __restrict__ A, const u16* __restrict__ W,
    const float* __restrict__ bias, float* __restrict__ C) {
  const int K = 1024, N = 1024;
  __shared__ u16 As[128][32];
  __shared__ u16 Bs[128][32];
  const int t = threadIdx.x;
  const int m0 = blockIdx.y * 128, n0 = blockIdx.x * 128;
  const int lane = t & 63, wid = t >> 6;
  const int wr = (wid >> 1) * 64, wc = (wid & 1) * 64;
  const int lr = lane & 15, lg = lane >> 4;
  const int ko = lg * 8;

  f32x4 acc[4][4];
  #pragma unroll
  for (int m = 0; m < 4; ++m)
    #pragma unroll
    for (int n = 0; n < 4; ++n)
      acc[m][n] = (f32x4){0.f, 0.f, 0.f, 0.f};

  for (int k0 = 0; k0 < K; k0 += 32) {
    __syncthreads();
    #pragma unroll
    for (int j = 0; j < 2; ++j) {
      int idx = t + j * 256;
      int r = idx >> 2, c8 = (idx & 3) * 8;
      size_t ldsoff = (size_t)(j * 256 + (t & ~63)) * 8;
      gll16(A + (size_t)(m0 + r) * K + k0 + c8, &As[0][0] + ldsoff);
      gll16(W + (size_t)(n0 + r) * K + k0 + c8, &Bs[0][0] + ldsoff);
    }
    __syncthreads();
    bf16x8 av[4], bv4[4];
    #pragma unroll
    for (int m = 0; m < 4; ++m)
      av[m] = *(const bf16x8*)&As[wr + m * 16 + lr][ko];
    #pragma unroll
    for (int n = 0; n < 4; ++n)
      bv4[n] = *(const bf16x8*)&Bs[wc + n * 16 + lr][ko];
    #pragma unroll
    for (int m = 0; m < 4; ++m)
      #pragma unroll
      for (int n = 0; n < 4; ++n)
        acc[m][n] = __builtin_amdgcn_mfma_f32_16x16x32_bf16(av[m], bv4[n], acc[m][n], 0, 0, 0);
  }

  const int rq = lg * 4;
  #pragma unroll
  for (int m = 0; m < 4; ++m) {
    #pragma unroll
    for (int r = 0; r < 4; ++r) {
      int row = m0 + wr + m * 16 + rq + r;
      float* cp = C + (size_t)row * N;
      #pragma unroll
      for (int n = 0; n < 4; ++n) {
        int col = n0 + wc + n * 16 + lr;
        cp[col] = acc[m][n][r] + bias[col];
      }
    }
  }
}

// ---------------------------------------------------------------------------
// vcat fp32 [B][4096][1024] -> bf16 transposed [B][16][64][4096]
// ---------------------------------------------------------------------------
__global__ __launch_bounds__(256) void repack_vt(
    const float* __restrict__ src, u16* __restrict__ dst) {
  __shared__ u16 T[64][72];
  const int t = threadIdx.x;
  const int kv0 = blockIdx.x * 64;
  const int bh = blockIdx.y;
  const int b = bh >> 4, h = bh & 15;
  #pragma unroll
  for (int it = 0; it < 4; ++it) {
    int idx = t + it * 256;
    int r = idx >> 4;
    int c4 = (idx & 15) * 4;
    float4 v = *(const float4*)(src + (size_t)(b * KVTOT + kv0 + r) * DMODEL + h * 64 + c4);
    *(uint2*)&T[r][c4] = make_uint2(cvt_pk_bf16(v.x, v.y), cvt_pk_bf16(v.z, v.w));
  }
  __syncthreads();
  #pragma unroll
  for (int it = 0; it < 2; ++it) {
    int idx = t + it * 256;
    int d = idx & 63;
    int kc8 = (idx >> 6) * 8;
    bf16x8 o;
    #pragma unroll
    for (int j = 0; j < 8; ++j) o[j] = (short)T[kc8 + j][d];
    *(bf16x8*)(dst + (size_t)((b * 16 + h) * 64 + d) * KVTOT + kv0 + kc8) = o;
  }
}

// ---------------------------------------------------------------------------
// MFMA flash attention v5: mask+max folded C-init, const-ones lsum fragment,
// defer-max, reg-prefetch K/V, setprio around MFMA, XCD-chunked swizzle.
// ---------------------------------------------------------------------------
__global__ __launch_bounds__(256) void attn_mfma(
    const u16* __restrict__ qh, const u16* __restrict__ kh,
    const u16* __restrict__ vt, const u64* __restrict__ mbits,
    u16* __restrict__ out) {
  __shared__ u16 Kl[64][72];
  __shared__ u16 Vl[64][72];
  __shared__ u16 Pl[4][16][72];
  const int t = threadIdx.x;
  const int wid = t >> 6, lane = t & 63;
  const int lr = lane & 15, lg = lane >> 4;
  const int fid = blockIdx.x;                      // 0..1023
  const int virt = (fid & 7) * 128 + (fid >> 3);   // XCD-chunked
  const int bh = virt >> 5, qt = virt & 31;
  const int b = bh >> 4, h = bh & 15;
  const int qw = qt * 64 + wid * 16;

  bf16x8 ones;
  #pragma unroll
  for (int j = 0; j < 8; ++j) ones[j] = (short)0x3F80;

  bf16x8 qf[2];
  {
    const u16* qp = qh + ((size_t)bh * QLEN + qw + lr) * 64 + lg * 8;
    qf[0] = *(const bf16x8*)qp;
    qf[1] = *(const bf16x8*)(qp + 32);
  }

  const size_t khb = (size_t)bh * KVTOT * 64;
  const size_t vtb = (size_t)bh * 64 * KVTOT;
  const u64* mrow = mbits + ((size_t)b * QLEN + qw + lr) * (KVTOT / 64);

  bf16x8 kreg[2], vreg[2];
  #pragma unroll
  for (int j = 0; j < 2; ++j) {
    int idx = t + j * 256;
    int r = idx >> 3, c8 = (idx & 7) * 8;
    kreg[j] = *(const bf16x8*)(kh + khb + (size_t)r * 64 + c8);
    vreg[j] = *(const bf16x8*)(vt + vtb + (size_t)r * KVTOT + c8);
  }

  float mprev = SENT;
  f32x4 oacc[5];
  #pragma unroll
  for (int dt = 0; dt < 5; ++dt) oacc[dt] = (f32x4){0.f, 0.f, 0.f, 0.f};

  for (int it = 0; it < KVTOT / 64; ++it) {
    u64 mb = mrow[it];
    __syncthreads();
    #pragma unroll
    for (int j = 0; j < 2; ++j) {
      int idx = t + j * 256;
      int r = idx >> 3, c8 = (idx & 7) * 8;
      *(bf16x8*)&Kl[r][c8] = kreg[j];
      *(bf16x8*)&Vl[r][c8] = vreg[j];
    }
    __syncthreads();
    if (it + 1 < KVTOT / 64) {
      int t0n = (it + 1) * 64;
      #pragma unroll
      for (int j = 0; j < 2; ++j) {
        int idx = t + j * 256;
        int r = idx >> 3, c8 = (idx & 7) * 8;
        kreg[j] = *(const bf16x8*)(kh + khb + (size_t)(t0n + r) * 64 + c8);
        vreg[j] = *(const bf16x8*)(vt + vtb + (size_t)r * KVTOT + t0n + c8);
      }
    }

    // QK^T with C-init = mask - mprev
    const u64 mq = mb >> (lg * 4);
    const float negm = -mprev, negmm = MASKC - mprev;
    f32x4 sacc[4];
    __builtin_amdgcn_s_setprio(1);
    #pragma unroll
    for (int tile = 0; tile < 4; ++tile) {
      unsigned nib = (unsigned)((mq >> (tile * 16)) & 0xFull);
      #pragma unroll
      for (int r = 0; r < 4; ++r)
        sacc[tile][r] = (nib & (1u << r)) ? negmm : negm;
      bf16x8 kf0 = *(const bf16x8*)&Kl[tile * 16 + lr][lg * 8];
      bf16x8 kf1 = *(const bf16x8*)&Kl[tile * 16 + lr][32 + lg * 8];
      sacc[tile] = __builtin_amdgcn_mfma_f32_16x16x32_bf16(kf0, qf[0], sacc[tile], 0, 0, 0);
      sacc[tile] = __builtin_amdgcn_mfma_f32_16x16x32_bf16(kf1, qf[1], sacc[tile], 0, 0, 0);
    }
    __builtin_amdgcn_s_setprio(0);

    float rmax = fmaxf(fmaxf(fmaxf(sacc[0][0], sacc[0][1]), fmaxf(sacc[0][2], sacc[0][3])),
                       fmaxf(fmaxf(sacc[1][0], sacc[1][1]), fmaxf(sacc[1][2], sacc[1][3])));
    rmax = fmaxf(rmax, fmaxf(fmaxf(fmaxf(sacc[2][0], sacc[2][1]), fmaxf(sacc[2][2], sacc[2][3])),
                             fmaxf(fmaxf(sacc[3][0], sacc[3][1]), fmaxf(sacc[3][2], sacc[3][3]))));
    rmax = fmaxf(rmax, __shfl_xor(rmax, 16));
    rmax = fmaxf(rmax, __shfl_xor(rmax, 32));

    if (__all(rmax <= 8.0f)) {
      #pragma unroll
      for (int tile = 0; tile < 4; ++tile) {
        float p0 = __expf(sacc[tile][0]);
        float p1 = __expf(sacc[tile][1]);
        float p2 = __expf(sacc[tile][2]);
        float p3 = __expf(sacc[tile][3]);
        *(uint2*)&Pl[wid][lr][tile * 16 + lg * 4] =
            make_uint2(cvt_pk_bf16(p0, p1), cvt_pk_bf16(p2, p3));
      }
    } else {
      float shift = fmaxf(rmax, 0.f);
      float corr = __expf(-shift);
      float cr[4];
      #pragma unroll
      for (int r = 0; r < 4; ++r) cr[r] = __shfl(corr, lg * 4 + r);
      #pragma unroll
      for (int dt = 0; dt < 5; ++dt)
        #pragma unroll
        for (int r = 0; r < 4; ++r) oacc[dt][r] *= cr[r];
      mprev += shift;
      #pragma unroll
      for (int tile = 0; tile < 4; ++tile) {
        float p0 = __expf(sacc[tile][0] - shift);
        float p1 = __expf(sacc[tile][1] - shift);
        float p2 = __expf(sacc[tile][2] - shift);
        float p3 = __expf(sacc[tile][3] - shift);
        *(uint2*)&Pl[wid][lr][tile * 16 + lg * 4] =
            make_uint2(cvt_pk_bf16(p0, p1), cvt_pk_bf16(p2, p3));
      }
    }

    // PV + lsum (ones fragment)
    bf16x8 pa0 = *(const bf16x8*)&Pl[wid][lr][lg * 8];
    bf16x8 pa1 = *(const bf16x8*)&Pl[wid][lr][32 + lg * 8];
    __builtin_amdgcn_s_setprio(1);
    #pragma unroll
    for (int dt = 0; dt < 4; ++dt) {
      bf16x8 vb0 = *(const bf16x8*)&Vl[dt * 16 + lr][lg * 8];
      bf16x8 vb1 = *(const bf16x8*)&Vl[dt * 16 + lr][32 + lg * 8];
      oacc[dt] = __builtin_amdgcn_mfma_f32_16x16x32_bf16(pa0, vb0, oacc[dt], 0, 0, 0);
      oacc[dt] = __builtin_amdgcn_mfma_f32_16x16x32_bf16(pa1, vb1, oacc[dt], 0, 0, 0);
    }
    oacc[4] = __builtin_amdgcn_mfma_f32_16x16x32_bf16(pa0, ones, oacc[4], 0, 0, 0);
    oacc[4] = __builtin_amdgcn_mfma_f32_16x16x32_bf16(pa1, ones, oacc[4], 0, 0, 0);
    __builtin_amdgcn_s_setprio(0);
  }

  #pragma unroll
  for (int r = 0; r < 4; ++r) {
    float inv = 1.f / oacc[4][r];
    #pragma unroll
    for (int dt = 0; dt < 4; ++dt)
      out[((size_t)b * QLEN + qw + lg * 4 + r) * DMODEL + h * 64 + dt * 16 + lr] =
          f2b(oacc[dt][r] * inv);
  }
}

// ---------------------------------------------------------------------------
extern "C" void kernel_launch(void* const* d_in, const int* in_sizes, int n_in,
                              void* d_out, int out_size, void* d_ws, size_t ws_size,
                              hipStream_t stream) {
  const float* q      = (const float*)d_in[0];
  const float* k      = (const float*)d_in[1];
  const float* v      = (const float*)d_in[2];
  const float* past_k = (const float*)d_in[3];
  const float* past_v = (const float*)d_in[4];
  const int*   mask   = (const int*)d_in[5];
  const float* Wq     = (const float*)d_in[6];
  const float* bq     = (const float*)d_in[7];
  const float* Wk     = (const float*)d_in[8];
  const float* bk     = (const float*)d_in[9];
  const float* Wv     = (const float*)d_in[10];
  const float* bv     = (const float*)d_in[11];
  const float* Wl     = (const float*)d_in[12];
  const float* bl     = (const float*)d_in[13];

  float* xout = (float*)d_out;                    // (B, Q, D)
  float* kcat = xout + 4194304;                   // (B, 4096, D)
  float* vcat = xout + 12582912;

  // ws (u16 units): attno 0..4M | qh 4..8M | kh 8..16M | vt 16..24M |
  //                 Wb 24..28M | mbits after (2MB)   total ≈ 58 MB
  u16* wsb = (u16*)d_ws;
  u16* attno = wsb;
  u16* qh = wsb + 4194304;
  u16* kh = wsb + 8388608;
  u16* vt = wsb + 16777216;
  u16* Wb = wsb + 25165824;
  u64* mbits = (u64*)(wsb + 29360128);

  copy_past<<<4096, 256, 0, stream>>>(past_k, past_v, kcat, vcat, kh);
  maskpack<<<65536, 256, 0, stream>>>(mask, mbits);
  w2b<<<dim3(512, 4), 256, 0, stream>>>(Wq, Wk, Wv, Wl, Wb);

  gemm_qkv<<<dim3(8, 32, 3), 256, 0, stream>>>(
      q, k, v, Wb, bq, bk, bv, qh, kcat, kh, vcat);

  repack_vt<<<dim3(64, 32), 256, 0, stream>>>(vcat, vt);

  attn_mfma<<<1024, 256, 0, stream>>>(qh, kh, vt, mbits, attno);

  gemm_out<<<dim3(8, 32), 256, 0, stream>>>(attno, Wb + 3145728, bl, xout);
}